// Round 2
// baseline (380.174 us; speedup 1.0000x reference)
//
#include <hip/hip_runtime.h>
#include <hip/hip_bf16.h>

#define SQi  2048
#define HNi  128
#define SBHi 4096            // element stride for s index: B*NH*HN
#define QBLK 64
#define KVB  64
#define SCALE 0.08838834764831845f   // 1/sqrt(128)
#define PP   72              // P_lds pitch (shorts): 144B == 16 mod 128 -> conflict-free b128

typedef __attribute__((ext_vector_type(4))) float f32x4;
typedef __attribute__((ext_vector_type(8))) short bf16x8;

__device__ __forceinline__ short f2bf(float f) {
    union { float f; unsigned u; } v; v.f = f;
    unsigned r = v.u + 0x7fffu + ((v.u >> 16) & 1u);
    return (short)(r >> 16);
}

// ---- pre-pass 1: K fp32 [s][b][h][d] -> bf16 Kb[bh][s][d] ----
__global__ __launch_bounds__(256)
void conv_k_kernel(const float* __restrict__ K, short* __restrict__ Kb) {
    int g  = (int)blockIdx.x * 256 + (int)threadIdx.x;   // 1,048,576 threads, 8 elems each
    int d8 = g & 15;
    int s  = (g >> 4) & 2047;
    int bh = g >> 15;
    const float* in = K + (size_t)s * SBHi + (size_t)(bh >> 4) * 2048 + (size_t)(bh & 15) * 128 + d8 * 8;
    f32x4 a = *(const f32x4*)in;
    f32x4 b = *(const f32x4*)(in + 4);
    bf16x8 h;
    #pragma unroll
    for (int i = 0; i < 4; ++i) { h[i] = f2bf(a[i]); h[4 + i] = f2bf(b[i]); }
    *(bf16x8*)(Kb + (size_t)bh * (SQi * HNi) + s * HNi + d8 * 8) = h;
}

// ---- pre-pass 2: V fp32 [s][b][h][d] -> bf16 Vt[bh][d][s] (LDS-tiled transpose) ----
__global__ __launch_bounds__(256)
void conv_vt_kernel(const float* __restrict__ V, short* __restrict__ Vt) {
    __shared__ float tile[64][33];
    const int t  = (int)threadIdx.x;
    const int s0 = (int)blockIdx.x * 64;
    const int d0 = (int)blockIdx.y * 32;
    const int bh = (int)blockIdx.z;
    const size_t in_b = (size_t)(bh >> 4) * 2048 + (size_t)(bh & 15) * 128 + d0;
    const int dl = t & 31, slr = t >> 5;
    #pragma unroll
    for (int r = 0; r < 8; ++r)
        tile[slr + r * 8][dl] = V[(size_t)(s0 + slr + r * 8) * SBHi + in_b + dl];
    __syncthreads();
    const int sl = t & 63, dlr = t >> 6;
    const size_t out_b = (size_t)bh * ((size_t)HNi * SQi) + (size_t)d0 * SQi + s0;
    #pragma unroll
    for (int r = 0; r < 8; ++r) {
        int d = dlr + r * 4;
        Vt[out_b + (size_t)d * SQi + sl] = f2bf(tile[sl][d]);
    }
}

// ---- main attention: barrier-free, K/Vt fragments straight from L2 ----
__global__ __launch_bounds__(256)
void attn_fwd2(const float* __restrict__ Q, const short* __restrict__ Kb,
               const short* __restrict__ Vt, float* __restrict__ O) {
    __shared__ __align__(16) short P_lds[4][16 * PP];

    // XCD-bijective swizzle: all q-blocks of one bh on one XCD; heavy q-tiles first
    const int bid = (int)blockIdx.x;          // 1024
    const int xcd = bid & 7;
    const int j   = bid >> 3;
    const int qt  = 31 - (j & 31);
    const int bh  = (j >> 5) * 8 + xcd;

    const size_t bh_q = (size_t)(bh >> 4) * 2048 + (size_t)(bh & 15) * 128;
    const short* Kbh = Kb + (size_t)bh * (SQi * HNi);
    const short* Vbh = Vt + (size_t)bh * ((size_t)HNi * SQi);

    const int t    = (int)threadIdx.x;
    const int lane = t & 63;
    const int wv   = t >> 6;
    const int l15  = lane & 15;
    const int lhi  = lane >> 4;

    // Q fragments (A operand), converted once
    bf16x8 q_frag[4];
    {
        const int qrow = qt * QBLK + wv * 16 + l15;
        const float* qp = Q + (size_t)qrow * SBHi + bh_q + lhi * 8;
        #pragma unroll
        for (int kk = 0; kk < 4; ++kk) {
            f32x4 a = *(const f32x4*)(qp + kk * 32);
            f32x4 b = *(const f32x4*)(qp + kk * 32 + 4);
            #pragma unroll
            for (int i = 0; i < 4; ++i) {
                q_frag[kk][i]     = f2bf(a[i]);
                q_frag[kk][4 + i] = f2bf(b[i]);
            }
        }
    }

    float m_r[4], l_part[4];
    #pragma unroll
    for (int r = 0; r < 4; ++r) { m_r[r] = -1e30f; l_part[r] = 0.f; }
    f32x4 o_acc[8];
    #pragma unroll
    for (int nn = 0; nn < 8; ++nn) o_acc[nn] = (f32x4){0.f, 0.f, 0.f, 0.f};

    const int row0 = qt * QBLK + wv * 16 + lhi * 4;   // this lane's first of 4 rows
    const int nt   = qt + 1;                           // KV tiles of 64 (uniform across waves)

    for (int it = 0; it < nt; ++it) {
        const int kv0 = it * KVB;

        // ---- S = Q K^T : 16 rows x 64 cols per wave ----
        f32x4 s_acc[4];
        #pragma unroll
        for (int kb = 0; kb < 4; ++kb) s_acc[kb] = (f32x4){0.f, 0.f, 0.f, 0.f};
        #pragma unroll
        for (int kb = 0; kb < 4; ++kb) {
            const short* kp = Kbh + (size_t)(kv0 + kb * 16 + l15) * HNi + lhi * 8;
            #pragma unroll
            for (int kk = 0; kk < 4; ++kk) {
                bf16x8 kf = *(const bf16x8*)(kp + kk * 32);
                s_acc[kb] = __builtin_amdgcn_mfma_f32_16x16x32_bf16(q_frag[kk], kf, s_acc[kb], 0, 0, 0);
            }
        }

        const bool need_mask = (it == nt - 1);

        // ---- online softmax (per-row groups of 16 lanes) ----
        #pragma unroll
        for (int r = 0; r < 4; ++r) {
            const int rg = row0 + r;
            float s0 = s_acc[0][r] * SCALE;
            float s1 = s_acc[1][r] * SCALE;
            float s2 = s_acc[2][r] * SCALE;
            float s3 = s_acc[3][r] * SCALE;
            if (need_mask) {
                const int c = kv0 + l15;
                if (c      > rg) s0 = -1e30f;
                if (c + 16 > rg) s1 = -1e30f;
                if (c + 32 > rg) s2 = -1e30f;
                if (c + 48 > rg) s3 = -1e30f;
            }
            float mx = fmaxf(fmaxf(s0, s1), fmaxf(s2, s3));
            #pragma unroll
            for (int m = 1; m < 16; m <<= 1) mx = fmaxf(mx, __shfl_xor(mx, m));
            // defer-max: only rescale when the running max grew by > 8
            if (mx > m_r[r] + 8.f) {
                const float corr = __expf(m_r[r] - mx);
                m_r[r] = mx;
                l_part[r] *= corr;
                #pragma unroll
                for (int nn = 0; nn < 8; ++nn) o_acc[nn][r] *= corr;
            }
            const float mm = m_r[r];
            const float p0 = __expf(s0 - mm);
            const float p1 = __expf(s1 - mm);
            const float p2 = __expf(s2 - mm);
            const float p3 = __expf(s3 - mm);
            l_part[r] += (p0 + p1) + (p2 + p3);
            const int rl = (lhi * 4 + r) * PP;
            P_lds[wv][rl + l15]      = f2bf(p0);
            P_lds[wv][rl + 16 + l15] = f2bf(p1);
            P_lds[wv][rl + 32 + l15] = f2bf(p2);
            P_lds[wv][rl + 48 + l15] = f2bf(p3);
        }

        // ---- O += P V : Vt fragments straight from global (L2) ----
        bf16x8 pa0 = *(const bf16x8*)&P_lds[wv][l15 * PP + lhi * 8];
        bf16x8 pa1 = *(const bf16x8*)&P_lds[wv][l15 * PP + 32 + lhi * 8];
        #pragma unroll
        for (int nn = 0; nn < 8; ++nn) {
            const short* vp = Vbh + (size_t)(nn * 16 + l15) * SQi + kv0 + lhi * 8;
            bf16x8 v0 = *(const bf16x8*)(vp);
            bf16x8 v1 = *(const bf16x8*)(vp + 32);
            o_acc[nn] = __builtin_amdgcn_mfma_f32_16x16x32_bf16(pa0, v0, o_acc[nn], 0, 0, 0);
            o_acc[nn] = __builtin_amdgcn_mfma_f32_16x16x32_bf16(pa1, v1, o_acc[nn], 0, 0, 0);
        }
    }

    // ---- epilogue: reduce l across the 16-lane group, then O / l ----
    #pragma unroll
    for (int r = 0; r < 4; ++r) {
        float ls = l_part[r];
        #pragma unroll
        for (int m = 1; m < 16; m <<= 1) ls += __shfl_xor(ls, m);
        const float inv = 1.0f / ls;
        float* op = O + (size_t)(row0 + r) * SBHi + bh_q + l15;
        #pragma unroll
        for (int nn = 0; nn < 8; ++nn) op[nn * 16] = o_acc[nn][r] * inv;
    }
}

extern "C" void kernel_launch(void* const* d_in, const int* in_sizes, int n_in,
                              void* d_out, int out_size, void* d_ws, size_t ws_size,
                              hipStream_t stream) {
    const float* q = (const float*)d_in[0];
    const float* k = (const float*)d_in[1];
    const float* v = (const float*)d_in[2];
    float* out = (float*)d_out;

    short* Kb = (short*)d_ws;                          // 16.78 MB
    short* Vt = Kb + (size_t)32 * SQi * HNi;           // +16.78 MB (total ~33.5 MB)

    conv_k_kernel<<<4096, 256, 0, stream>>>(k, Kb);
    conv_vt_kernel<<<dim3(SQi / 64, HNi / 32, 32), 256, 0, stream>>>(v, Vt);
    attn_fwd2<<<1024, 256, 0, stream>>>(q, Kb, Vt, out);
}

// Round 3
// 107.457 us; speedup vs baseline: 3.5379x; 3.5379x over previous
//
#include <hip/hip_runtime.h>
#include <hip/hip_bf16.h>

#define SQi  2048
#define SBHi 4096            // element stride for s index: B*NH*HN
#define SCALE 0.08838834764831845f   // 1/sqrt(128)
#define PP   72              // P_lds pitch (shorts): conflict-free-ish

typedef __attribute__((ext_vector_type(4))) float f32x4;
typedef __attribute__((ext_vector_type(8))) short bf16x8;

__device__ __forceinline__ short f2bf(float f) {
    union { float f; unsigned u; } v; v.f = f;
    unsigned r = v.u + 0x7fffu + ((v.u >> 16) & 1u);
    return (short)(r >> 16);
}

// ---- pre-pass 1: K fp32 [s][b][h][d] -> fragment-ordered bf16 KF[bh][t16][kk][lane][8]
// frag(t16,kk): 16 kv-rows x 32 d; lane(l15=kv row, lhi=d sub-chunk)
__global__ __launch_bounds__(256)
void conv_kf(const float* __restrict__ K, short* __restrict__ KF) {
    const int g = (int)blockIdx.x * 256 + (int)threadIdx.x;   // 2^20 threads
    const int lane = g & 63, kk = (g >> 6) & 3, t16 = (g >> 8) & 127, bh = g >> 15;
    const int s = t16 * 16 + (lane & 15);
    const int d = kk * 32 + (lane >> 4) * 8;
    const float* in = K + (size_t)s * SBHi + (size_t)(bh >> 4) * 2048 + (bh & 15) * 128 + d;
    f32x4 a = *(const f32x4*)in;
    f32x4 b = *(const f32x4*)(in + 4);
    bf16x8 h;
    #pragma unroll
    for (int i = 0; i < 4; ++i) { h[i] = f2bf(a[i]); h[4 + i] = f2bf(b[i]); }
    *(bf16x8*)(KF + (size_t)g * 8) = h;   // g order == [bh][t16][kk][lane]
}

// ---- pre-pass 2: V fp32 [s][b][h][d] -> fragment-ordered bf16 VF[bh][t32][nn][lane][8]
// frag(t32,nn): 32 kv (k-dim) x 16 d (cols); lane(l15=d col, lhi=kv sub-chunk)
__global__ __launch_bounds__(256)
void conv_vf(const float* __restrict__ V, short* __restrict__ VF) {
    const int g = (int)blockIdx.x * 256 + (int)threadIdx.x;   // 2^20 threads
    const int lane = g & 63, nn = (g >> 6) & 7, t32 = (g >> 9) & 63, bh = g >> 15;
    const int s = t32 * 32 + (lane >> 4) * 8;
    const int d = nn * 16 + (lane & 15);
    const float* in = V + (size_t)s * SBHi + (size_t)(bh >> 4) * 2048 + (bh & 15) * 128 + d;
    bf16x8 h;
    #pragma unroll
    for (int e = 0; e < 8; ++e) h[e] = f2bf(in[(size_t)e * SBHi]);
    *(bf16x8*)(VF + (size_t)g * 8) = h;   // g order == [bh][t32][nn][lane]
}

// ---- main attention: coalesced fragment loads, paired q-tiles (uniform work), barrier-free
__global__ __launch_bounds__(256)
void attn_fwd3(const float* __restrict__ Q, const short* __restrict__ KF,
               const short* __restrict__ VF, float* __restrict__ O) {
    __shared__ __align__(16) short P_lds[4][16 * PP];

    const int bid = (int)blockIdx.x;          // 512 blocks
    const int xcd = bid & 7, j = bid >> 3;    // j in [0,64)
    const int bh  = xcd + 8 * (j >> 4);       // 4 bh per XCD -> KF+VF 4MB ~ one L2
    const int pr  = j & 15;                   // pair id: q-tiles (pr, 31-pr) -> 33 tiles uniform

    const size_t bh_q = (size_t)(bh >> 4) * 2048 + (size_t)(bh & 15) * 128;
    const short* KFb = KF + (size_t)bh * 262144;
    const short* VFb = VF + (size_t)bh * 262144;

    const int t = (int)threadIdx.x;
    const int lane = t & 63, wv = t >> 6, l15 = lane & 15, lhi = lane >> 4;

    for (int half = 0; half < 2; ++half) {
        const int qt = half ? (31 - pr) : pr;

        // Q fragments, scale folded in
        bf16x8 q_frag[4];
        {
            const int qrow = qt * 64 + wv * 16 + l15;
            const float* qp = Q + (size_t)qrow * SBHi + bh_q + lhi * 8;
            #pragma unroll
            for (int kk = 0; kk < 4; ++kk) {
                f32x4 a = *(const f32x4*)(qp + kk * 32);
                f32x4 b = *(const f32x4*)(qp + kk * 32 + 4);
                #pragma unroll
                for (int i = 0; i < 4; ++i) {
                    q_frag[kk][i]     = f2bf(a[i] * SCALE);
                    q_frag[kk][4 + i] = f2bf(b[i] * SCALE);
                }
            }
        }

        float m_r[4], l_part[4];
        #pragma unroll
        for (int r = 0; r < 4; ++r) { m_r[r] = -1e30f; l_part[r] = 0.f; }
        f32x4 o_acc[8];
        #pragma unroll
        for (int nn = 0; nn < 8; ++nn) o_acc[nn] = (f32x4){0.f, 0.f, 0.f, 0.f};

        const int row0 = qt * 64 + wv * 16 + lhi * 4;

        for (int it = 0; it <= qt; ++it) {
            // ---- S = Q K^T : 16 rows x 64 cols, coalesced K fragment loads ----
            f32x4 s_acc[4];
            #pragma unroll
            for (int kb = 0; kb < 4; ++kb) s_acc[kb] = (f32x4){0.f, 0.f, 0.f, 0.f};
            const short* kbase = KFb + (size_t)it * 8192 + lane * 8;
            #pragma unroll
            for (int kb = 0; kb < 4; ++kb) {
                #pragma unroll
                for (int kk = 0; kk < 4; ++kk) {
                    bf16x8 kfr = *(const bf16x8*)(kbase + (kb * 4 + kk) * 512);
                    s_acc[kb] = __builtin_amdgcn_mfma_f32_16x16x32_bf16(q_frag[kk], kfr, s_acc[kb], 0, 0, 0);
                }
            }

            // ---- V fragment loads issued early: latency hides under softmax ----
            bf16x8 vfr0[8], vfr1[8];
            const short* vbase = VFb + (size_t)it * 8192 + lane * 8;
            #pragma unroll
            for (int nn = 0; nn < 8; ++nn) {
                vfr0[nn] = *(const bf16x8*)(vbase + nn * 512);
                vfr1[nn] = *(const bf16x8*)(vbase + (8 + nn) * 512);
            }

            const bool need_mask = (it == qt);

            // ---- online softmax (16-lane groups per row) ----
            #pragma unroll
            for (int r = 0; r < 4; ++r) {
                const int rg = row0 + r;
                float s0 = s_acc[0][r];
                float s1 = s_acc[1][r];
                float s2 = s_acc[2][r];
                float s3 = s_acc[3][r];
                if (need_mask) {
                    const int c = it * 64 + l15;
                    if (c      > rg) s0 = -1e30f;
                    if (c + 16 > rg) s1 = -1e30f;
                    if (c + 32 > rg) s2 = -1e30f;
                    if (c + 48 > rg) s3 = -1e30f;
                }
                float mx = fmaxf(fmaxf(s0, s1), fmaxf(s2, s3));
                #pragma unroll
                for (int m = 1; m < 16; m <<= 1) mx = fmaxf(mx, __shfl_xor(mx, m));
                if (mx > m_r[r] + 8.f) {            // defer-max
                    const float corr = __expf(m_r[r] - mx);
                    m_r[r] = mx;
                    l_part[r] *= corr;
                    #pragma unroll
                    for (int nn = 0; nn < 8; ++nn) o_acc[nn][r] *= corr;
                }
                const float mm = m_r[r];
                const float p0 = __expf(s0 - mm);
                const float p1 = __expf(s1 - mm);
                const float p2 = __expf(s2 - mm);
                const float p3 = __expf(s3 - mm);
                l_part[r] += (p0 + p1) + (p2 + p3);
                const int rl = (lhi * 4 + r) * PP;
                P_lds[wv][rl + l15]      = f2bf(p0);
                P_lds[wv][rl + 16 + l15] = f2bf(p1);
                P_lds[wv][rl + 32 + l15] = f2bf(p2);
                P_lds[wv][rl + 48 + l15] = f2bf(p3);
            }

            // ---- O += P V with preloaded V fragments ----
            bf16x8 pa0 = *(const bf16x8*)&P_lds[wv][l15 * PP + lhi * 8];
            bf16x8 pa1 = *(const bf16x8*)&P_lds[wv][l15 * PP + 32 + lhi * 8];
            #pragma unroll
            for (int nn = 0; nn < 8; ++nn) {
                o_acc[nn] = __builtin_amdgcn_mfma_f32_16x16x32_bf16(pa0, vfr0[nn], o_acc[nn], 0, 0, 0);
                o_acc[nn] = __builtin_amdgcn_mfma_f32_16x16x32_bf16(pa1, vfr1[nn], o_acc[nn], 0, 0, 0);
            }
        }

        // ---- epilogue: reduce l across the 16-lane group, then O / l ----
        #pragma unroll
        for (int r = 0; r < 4; ++r) {
            float ls = l_part[r];
            #pragma unroll
            for (int m = 1; m < 16; m <<= 1) ls += __shfl_xor(ls, m);
            const float inv = 1.0f / ls;
            float* op = O + (size_t)(row0 + r) * SBHi + bh_q + l15;
            #pragma unroll
            for (int nn = 0; nn < 8; ++nn) op[nn * 16] = o_acc[nn][r] * inv;
        }
    }
}

extern "C" void kernel_launch(void* const* d_in, const int* in_sizes, int n_in,
                              void* d_out, int out_size, void* d_ws, size_t ws_size,
                              hipStream_t stream) {
    const float* q = (const float*)d_in[0];
    const float* k = (const float*)d_in[1];
    const float* v = (const float*)d_in[2];
    float* out = (float*)d_out;

    short* KF = (short*)d_ws;                       // 16.78 MB
    short* VF = KF + (size_t)32 * 262144;           // +16.78 MB (total ~33.5 MB)

    conv_kf<<<4096, 256, 0, stream>>>(k, KF);
    conv_vf<<<4096, 256, 0, stream>>>(v, VF);
    attn_fwd3<<<512, 256, 0, stream>>>(q, KF, VF, out);
}